// Round 18
// baseline (399.288 us; speedup 1.0000x reference)
//
#include <hip/hip_runtime.h>
#include <hip/hip_bf16.h>
#include <cstdint>
#include <cstddef>

#define BATCH 8
#define FRAMES 128
#define TOK (BATCH*FRAMES)   // 1024
#define NM 60
#define VF 196
#define DD 256
#define EDIM 512
#define NSTATE 16
#define DTRANK 16
#define NLAYER 4

typedef __attribute__((ext_vector_type(8))) short short8v;
typedef __attribute__((ext_vector_type(4))) float f32x4;

__device__ __forceinline__ unsigned short f2bf(float f) {
  unsigned x = __float_as_uint(f);
  unsigned r = (x + 0x7FFFu + ((x >> 16) & 1u)) >> 16;
  return (unsigned short)r;
}
__device__ __forceinline__ float bf2f(unsigned short u) {
  return __uint_as_float((unsigned)u << 16);
}

// ---------------------------------------------------------------------------
// pack_all: mamba weights + conv weights -> bf16 MFMA fragment order.
// ---------------------------------------------------------------------------
__global__ void pack_all(const float* __restrict__ ipF, const float* __restrict__ ipR,
                         const float* __restrict__ opF, const float* __restrict__ opR,
                         const float* __restrict__ xpF, const float* __restrict__ xpR,
                         const float* __restrict__ w2, const float* __restrict__ w1,
                         unsigned short* __restrict__ Wip, unsigned short* __restrict__ Wop,
                         unsigned short* __restrict__ Wxp, unsigned short* __restrict__ Wb,
                         unsigned short* __restrict__ Wb1) {
  int id = blockIdx.x * 256 + threadIdx.x;
  if (id < 262144) {                     // in_proj
    int dl = id >> 15, r = id & 32767;
    int ntile = r >> 9, kt = (r >> 6) & 7, lane = r & 63;
    int dir = dl >> 2, layer = dl & 3;
    const float* src = (dir ? ipR : ipF) + (size_t)layer * 1024 * 256
                       + (size_t)(ntile * 16 + (lane & 15)) * 256 + kt * 32 + (lane >> 4) * 8;
    unsigned u[4];
#pragma unroll
    for (int p = 0; p < 4; ++p)
      u[p] = (unsigned)f2bf(src[2 * p]) | ((unsigned)f2bf(src[2 * p + 1]) << 16);
    uint4 v = {u[0], u[1], u[2], u[3]};
    *(uint4*)(Wip + (size_t)id * 8) = v;
  } else if (id < 262144 + 131072) {     // out_proj
    int id2 = id - 262144;
    int dl = id2 >> 14, rr = id2 & 16383;
    int ntile = rr >> 10, kt = (rr >> 6) & 15, lane = rr & 63;
    int dir = dl >> 2, layer = dl & 3;
    const float* src = (dir ? opR : opF) + (size_t)layer * 256 * 512
                       + (size_t)(ntile * 16 + (lane & 15)) * 512 + kt * 32 + (lane >> 4) * 8;
    unsigned u[4];
#pragma unroll
    for (int p = 0; p < 4; ++p)
      u[p] = (unsigned)f2bf(src[2 * p]) | ((unsigned)f2bf(src[2 * p + 1]) << 16);
    uint4 v = {u[0], u[1], u[2], u[3]};
    *(uint4*)(Wop + (size_t)id2 * 8) = v;
  } else if (id < 262144 + 131072 + 24576) {  // x_proj (48 x 512)
    int id3 = id - 262144 - 131072;
    int dl = id3 / 3072, rr = id3 % 3072;
    int ntile = rr >> 10, kt = (rr >> 6) & 15, lane = rr & 63;
    int dir = dl >> 2, layer = dl & 3;
    const float* src = (dir ? xpR : xpF) + (size_t)layer * 48 * 512
                       + (size_t)(ntile * 16 + (lane & 15)) * 512 + kt * 32 + (lane >> 4) * 8;
    unsigned u[4];
#pragma unroll
    for (int p = 0; p < 4; ++p)
      u[p] = (unsigned)f2bf(src[2 * p]) | ((unsigned)f2bf(src[2 * p + 1]) << 16);
    uint4 v = {u[0], u[1], u[2], u[3]};
    *(uint4*)(Wxp + (size_t)id3 * 8) = v;
  } else if (id < 417792 + 2304) {       // w2 conv2 A-frags
    int id4 = id - 417792;
    int lane = id4 & 63;
    int mt = (id4 >> 6) & 3;
    int sh = id4 >> 8;
    int dy = sh / 3, dx = sh % 3;
    int oc = mt * 16 + (lane & 15);
    int ic0 = (lane >> 4) * 8;
    unsigned u[4];
#pragma unroll
    for (int p = 0; p < 4; ++p) {
      unsigned short lo = f2bf(w2[((oc * 32 + ic0 + 2 * p) * 3 + dy) * 3 + dx]);
      unsigned short hi = f2bf(w2[((oc * 32 + ic0 + 2 * p + 1) * 3 + dy) * 3 + dx]);
      u[p] = (unsigned)lo | ((unsigned)hi << 16);
    }
    uint4 v = {u[0], u[1], u[2], u[3]};
    *(uint4*)(Wb + (size_t)id4 * 8) = v;
  } else if (id < 417792 + 2304 + 128) { // w1 conv1 A-frags (K=32, k>=27 zero)
    int id5 = id - 417792 - 2304;
    int mt = id5 >> 6, lane = id5 & 63;
    int oc = mt * 16 + (lane & 15);
    int ko = lane >> 4;
    unsigned u[4];
#pragma unroll
    for (int p = 0; p < 4; ++p) {
      int k0 = ko * 8 + 2 * p, k1 = k0 + 1;
      unsigned short lo = (k0 < 27) ? f2bf(w1[oc * 27 + k0]) : 0;
      unsigned short hi = (k1 < 27) ? f2bf(w1[oc * 27 + k1]) : 0;
      u[p] = (unsigned)lo | ((unsigned)hi << 16);
    }
    uint4 v = {u[0], u[1], u[2], u[3]};
    *(uint4*)(Wb1 + (size_t)id5 * 8) = v;
  }
}

// ---------------------------------------------------------------------------
// conv1_mfma: conv(3->32,3x3,SAME)+bias+relu+maxpool2 via K=32 MFMA.
// C1ICS padded 4488->4496 u16 (ic-plane stride = 8 mod 32 dwords: octet
// bank ranges separated).
// ---------------------------------------------------------------------------
#define C1RS 68
#define C1ICS 4496
__global__ __launch_bounds__(256) void conv1_mfma(
    const float* __restrict__ video, const unsigned short* __restrict__ Wb1,
    const float* __restrict__ b1, unsigned short* __restrict__ X1)
{
  __shared__ unsigned short ldsu[3 * C1ICS + 96];
  const int img = blockIdx.x, t = threadIdx.x;
  const float* vin = video + (size_t)img * 12288;
  const int lane = t & 63, wv = t >> 6;
  const int col = lane & 15, ko = lane >> 4;

  for (int i = t; i < (3 * C1ICS + 96) / 2; i += 256) ((unsigned*)ldsu)[i] = 0;
  __syncthreads();
#pragma unroll
  for (int i = 0; i < 12; ++i) {
    int c = i * 256 + t;
    int ic = c >> 10, rem = c & 1023, gy = rem >> 4, c4 = rem & 15;
    float4 v = *(const float4*)(vin + ic * 4096 + gy * 64 + c4 * 4);
    unsigned lo = (unsigned)f2bf(v.x) | ((unsigned)f2bf(v.y) << 16);
    unsigned hi = (unsigned)f2bf(v.z) | ((unsigned)f2bf(v.w) << 16);
    int di = ic * C1ICS + (gy + 1) * C1RS + 4 + c4 * 4;
    *(uint2*)(ldsu + di) = (uint2){lo, hi};
  }

  short8v A0 = *(const short8v*)(Wb1 + (size_t)(0 * 64 + lane) * 8);
  short8v A1 = *(const short8v*)(Wb1 + (size_t)(1 * 64 + lane) * 8);
  float bia[2][4];
#pragma unroll
  for (int mt = 0; mt < 2; ++mt)
#pragma unroll
    for (int r = 0; r < 4; ++r) bia[mt][r] = b1[mt * 16 + ko * 4 + r];

  int offs[8];
#pragma unroll
  for (int j = 0; j < 8; ++j) {
    int k = ko * 8 + j;
    int o = 0;
    if (k < 27) {
      int ic = k / 9, tap = k - ic * 9;
      int dy = tap / 3, dx = tap - dy * 3;
      o = ic * C1ICS + dy * C1RS + dx + 3;
    }
    offs[j] = o;
  }
  __syncthreads();

  f32x4 z4 = {0.f, 0.f, 0.f, 0.f};
#pragma unroll 1
  for (int rp = 0; rp < 8; ++rp) {
    const int y0 = wv * 16 + rp * 2;
#pragma unroll
    for (int xg = 0; xg < 4; ++xg) {
      const int bse = y0 * C1RS + xg * 16 + col;
      short8v vb0, vb1;
#pragma unroll
      for (int j = 0; j < 8; ++j) {
        vb0[j] = (short)ldsu[bse + offs[j]];
        vb1[j] = (short)ldsu[bse + C1RS + offs[j]];
      }
      f32x4 c00 = __builtin_amdgcn_mfma_f32_16x16x32_bf16(A0, vb0, z4, 0, 0, 0);
      f32x4 c10 = __builtin_amdgcn_mfma_f32_16x16x32_bf16(A1, vb0, z4, 0, 0, 0);
      f32x4 c01 = __builtin_amdgcn_mfma_f32_16x16x32_bf16(A0, vb1, z4, 0, 0, 0);
      f32x4 c11 = __builtin_amdgcn_mfma_f32_16x16x32_bf16(A1, vb1, z4, 0, 0, 0);
      const int py = wv * 8 + rp;
      const int pxp = xg * 8 + (col >> 1);
#pragma unroll
      for (int mt = 0; mt < 2; ++mt) {
        f32x4 ca = mt ? c10 : c00;
        f32x4 cb = mt ? c11 : c01;
        unsigned pk[2];
#pragma unroll
        for (int r = 0; r < 4; ++r) {
          float va = fmaxf(ca[r] + bia[mt][r], 0.f);
          float vb = fmaxf(cb[r] + bia[mt][r], 0.f);
          float v = fmaxf(va, vb);
          v = fmaxf(v, __shfl_xor(v, 1, 64));
          unsigned short u = f2bf(v);
          if ((r & 1) == 0) pk[r >> 1] = (unsigned)u;
          else              pk[r >> 1] |= ((unsigned)u << 16);
        }
        if ((col & 1) == 0) {
          uint2 o = {pk[0], pk[1]};
          *(uint2*)(X1 + ((size_t)(img * 1024 + py * 32 + pxp) * 32 + mt * 16 + ko * 4)) = o;
        }
      }
    }
  }
}

// ---------------------------------------------------------------------------
// conv2_k: HALF-IMAGE + XOR-swizzled [px][32ch] LDS (c' = (px*4+kg)^(px&7),
// bijective, both sides) + q-split acc[4][2] (VGPR ~128 = 16-wave tier).
// 40KB LDS -> 4 blocks/CU. Mean via 2-way atomicAdd (commutative = exact).
// ---------------------------------------------------------------------------
#define C2LDS (18 * 34 * 32)   // u16 = 39168 B
__global__ __launch_bounds__(256) void conv2_k(
    const unsigned short* __restrict__ X1, const unsigned short* __restrict__ Wb,
    const float* __restrict__ b2, float* __restrict__ feat)
{
  __shared__ unsigned short xs[C2LDS];
  __shared__ float part[256];
  const int img = blockIdx.x >> 1, h = blockIdx.x & 1;
  const int t = threadIdx.x;
  const int lane = t & 63, wv = t >> 6;
  const int kg = lane >> 4, l15 = lane & 15;

  // zero borders (swizzled)
  {
    uint4 z = {0, 0, 0, 0};
    uint4* dst = (uint4*)xs;
    const int rz = h ? 17 : 0;
    for (int j = t; j < 70; j += 256) {
      int r, c;
      if (j < 36) { r = j >> 1; c = (j & 1) ? 33 : 0; }
      else        { r = rz;     c = j - 36; }
      int px = r * 34 + c;
#pragma unroll
      for (int g = 0; g < 4; ++g)
        dst[(px * 4 + g) ^ (px & 7)] = z;
    }
  }
  // stage 17 valid X1 rows (swizzled dest)
  {
    const uint4* src = (const uint4*)(X1 + (size_t)img * 32768);
    uint4* dst = (uint4*)xs;
    for (int i = t; i < 17 * 128; i += 256) {
      int vr = i >> 7, rem = i & 127;
      int c = rem >> 2, g = rem & 3;
      int x1row = h ? (15 + vr) : vr;
      int ldsRow = h ? vr : (vr + 1);
      int px = ldsRow * 34 + c + 1;
      dst[(px * 4 + g) ^ (px & 7)] = src[(x1row * 32 + c) * 4 + g];
    }
  }
  __syncthreads();

  float bia[4][4];
#pragma unroll
  for (int mt = 0; mt < 4; ++mt)
#pragma unroll
    for (int r = 0; r < 4; ++r) bia[mt][r] = b2[mt * 16 + kg * 4 + r];

  float msum[4][4];
#pragma unroll
  for (int mt = 0; mt < 4; ++mt)
#pragma unroll
    for (int r = 0; r < 4; ++r) msum[mt][r] = 0.f;

#pragma unroll 1
  for (int hf = 0; hf < 2; ++hf) {
#pragma unroll 1
    for (int qq = 0; qq < 2; ++qq) {           // pool pair {qq, qq+2}
      f32x4 acc[4][2];
#pragma unroll
      for (int mt = 0; mt < 4; ++mt) {
        acc[mt][0] = (f32x4){0.f, 0.f, 0.f, 0.f};
        acc[mt][1] = (f32x4){0.f, 0.f, 0.f, 0.f};
      }
      int Pq[2];
#pragma unroll
      for (int j = 0; j < 2; ++j) {
        int qsel = qq + j * 2;
        int p = (wv * 8 + hf * 4 + qsel) * 16 + l15;   // local frag px 0..511
        int ly = p >> 5, x = p & 31;                    // local conv row 0..15
        Pq[j] = ly * 34 + x;                            // dy=dx=0 base (lds px)
      }
#pragma unroll
      for (int sh = 0; sh < 9; ++sh) {
        const int dy = sh / 3, dx = sh % 3;
        const int off = dy * 34 + dx;
        short8v Af[4];
#pragma unroll
        for (int mt = 0; mt < 4; ++mt)
          Af[mt] = *(const short8v*)(Wb + ((size_t)(sh * 4 + mt) * 64 + lane) * 8);
        int p0 = Pq[0] + off;
        int c0 = (p0 * 4 + kg) ^ (p0 & 7);
        short8v B0 = *(const short8v*)(xs + (size_t)c0 * 8);
        int p1 = Pq[1] + off;
        int c1 = (p1 * 4 + kg) ^ (p1 & 7);
        short8v B1 = *(const short8v*)(xs + (size_t)c1 * 8);
#pragma unroll
        for (int mt = 0; mt < 4; ++mt) {
          acc[mt][0] = __builtin_amdgcn_mfma_f32_16x16x32_bf16(Af[mt], B0, acc[mt][0], 0, 0, 0);
          acc[mt][1] = __builtin_amdgcn_mfma_f32_16x16x32_bf16(Af[mt], B1, acc[mt][1], 0, 0, 0);
        }
      }
#pragma unroll
      for (int mt = 0; mt < 4; ++mt)
#pragma unroll
        for (int r = 0; r < 4; ++r) {
          float va = fmaxf(acc[mt][0][r] + bia[mt][r], 0.f);
          float vb = fmaxf(acc[mt][1][r] + bia[mt][r], 0.f);
          float v = fmaxf(va, vb);
          v = fmaxf(v, __shfl_xor(v, 1, 64));   // x-pair pool
          msum[mt][r] += v;                      // counted twice
        }
    }
  }
#pragma unroll
  for (int mt = 0; mt < 4; ++mt)
#pragma unroll
    for (int r = 0; r < 4; ++r) {
      float v = msum[mt][r];
      v += __shfl_xor(v, 1, 64);
      v += __shfl_xor(v, 2, 64);
      v += __shfl_xor(v, 4, 64);
      v += __shfl_xor(v, 8, 64);
      if (l15 == 0) part[wv * 64 + mt * 16 + kg * 4 + r] = v * 0.5f;
    }
  __syncthreads();
  if (t < 64)
    atomicAdd(&feat[(size_t)img * 64 + t],
              (part[t] + part[64 + t] + part[128 + t] + part[192 + t]) * (1.f / 256.f));
}

// ---------------------------------------------------------------------------
// fcgemm_k: feat @ fcw^T + fcb -> xf / reversed xr; audio cols fused.
// ---------------------------------------------------------------------------
__global__ __launch_bounds__(256) void fcgemm_k(
    const float* __restrict__ A, const float* __restrict__ B,
    const float* __restrict__ bias, const float* __restrict__ audio,
    float* __restrict__ xf, float* __restrict__ xr)
{
  __shared__ float sA[16][68];
  __shared__ float sB[16][68];
  const int t = threadIdx.x;
  const int m0 = blockIdx.x * 64;
  const int n0 = blockIdx.y * 64;
  const int tx = t & 15, ty = t >> 4;
  const int lk = t & 15, lr = t >> 4;
  float acc[4][4] = {};
  for (int k0 = 0; k0 < 64; k0 += 16) {
#pragma unroll
    for (int rr = 0; rr < 4; ++rr) {
      int m = m0 + lr + rr * 16;
      sA[lk][lr + rr * 16] = A[(size_t)m * 64 + k0 + lk];
      int n = n0 + lr + rr * 16;
      sB[lk][lr + rr * 16] = (n < VF) ? B[(size_t)n * 64 + k0 + lk] : 0.f;
    }
    __syncthreads();
#pragma unroll
    for (int kk = 0; kk < 16; ++kk) {
      float a0 = sA[kk][ty*4+0], a1 = sA[kk][ty*4+1], a2 = sA[kk][ty*4+2], a3 = sA[kk][ty*4+3];
      float b0 = sB[kk][tx*4+0], b1 = sB[kk][tx*4+1], b2 = sB[kk][tx*4+2], b3 = sB[kk][tx*4+3];
      acc[0][0]=fmaf(a0,b0,acc[0][0]); acc[0][1]=fmaf(a0,b1,acc[0][1]); acc[0][2]=fmaf(a0,b2,acc[0][2]); acc[0][3]=fmaf(a0,b3,acc[0][3]);
      acc[1][0]=fmaf(a1,b0,acc[1][0]); acc[1][1]=fmaf(a1,b1,acc[1][1]); acc[1][2]=fmaf(a1,b2,acc[1][2]); acc[1][3]=fmaf(a1,b3,acc[1][3]);
      acc[2][0]=fmaf(a2,b0,acc[2][0]); acc[2][1]=fmaf(a2,b1,acc[2][1]); acc[2][2]=fmaf(a2,b2,acc[2][2]); acc[2][3]=fmaf(a2,b3,acc[2][3]);
      acc[3][0]=fmaf(a3,b0,acc[3][0]); acc[3][1]=fmaf(a3,b1,acc[3][1]); acc[3][2]=fmaf(a3,b2,acc[3][2]); acc[3][3]=fmaf(a3,b3,acc[3][3]);
    }
    __syncthreads();
  }
#pragma unroll
  for (int i = 0; i < 4; ++i) {
    int m = m0 + ty * 4 + i;
    int b = m >> 7, l = m & 127;
    int mr = (b << 7) + (127 - l);
#pragma unroll
    for (int j = 0; j < 4; ++j) {
      int n = n0 + tx * 4 + j;
      float v;
      if (n < VF)       v = acc[i][j] + bias[n];
      else              v = audio[(size_t)b * (FRAMES * NM) + l * NM + (n - VF)];
      xf[(size_t)m * DD + n] = v;
      xr[(size_t)mr * DD + n] = v;
    }
  }
}

// ---------------------------------------------------------------------------
// inproj_mfma3: fused rmsnorm + bf16 MFMA GEMM. Writes xz as BF16.
// ---------------------------------------------------------------------------
__global__ __launch_bounds__(256) void inproj_mfma3(
    const float* __restrict__ xF, const float* __restrict__ xR,
    const float* __restrict__ nwF, const float* __restrict__ nwR,
    const unsigned short* __restrict__ Wip, int layer,
    unsigned short* __restrict__ xzF, unsigned short* __restrict__ xzR)
{
  const int dir = blockIdx.z;
  const float* x = dir ? xR : xF;
  const float* nw = dir ? nwR : nwF;
  unsigned short* xz = dir ? xzR : xzF;
  __shared__ unsigned short sa[32 * 16 * 8];   // 8KB
  const int t = threadIdx.x;
  const int tok0 = blockIdx.x * 16;
  {
    const int tk = t >> 4, l16 = t & 15;
    const float* row = x + (size_t)(tok0 + tk) * DD + l16 * 16;
    float v[16];
    float ss = 0.f;
#pragma unroll
    for (int i = 0; i < 4; ++i) {
      float4 f = ((const float4*)row)[i];
      v[4*i] = f.x; v[4*i+1] = f.y; v[4*i+2] = f.z; v[4*i+3] = f.w;
      ss += f.x*f.x + f.y*f.y + f.z*f.z + f.w*f.w;
    }
    ss += __shfl_xor(ss, 1, 16);
    ss += __shfl_xor(ss, 2, 16);
    ss += __shfl_xor(ss, 4, 16);
    ss += __shfl_xor(ss, 8, 16);
    float scale = rsqrtf(ss * (1.f / DD) + 1e-5f);
    const float* nwp = nw + l16 * 16;
#pragma unroll
    for (int hh = 0; hh < 2; ++hh) {
      unsigned ub[4];
#pragma unroll
      for (int p = 0; p < 4; ++p) {
        unsigned short lo = f2bf(v[hh*8 + 2*p]     * scale * nwp[hh*8 + 2*p]);
        unsigned short hi = f2bf(v[hh*8 + 2*p + 1] * scale * nwp[hh*8 + 2*p + 1]);
        ub[p] = (unsigned)lo | ((unsigned)hi << 16);
      }
      int k0 = l16 * 16 + hh * 8;
      int kt = k0 >> 5, oct = (k0 >> 3) & 3;
      uint4 w4 = {ub[0], ub[1], ub[2], ub[3]};
      *(uint4*)(sa + ((size_t)(kt * 4 + oct) * 16 + tk) * 8) = w4;
    }
  }
  __syncthreads();
  const int lane = t & 63, w = t >> 6;
  short8v af[8];
#pragma unroll
  for (int kt = 0; kt < 8; ++kt)
    af[kt] = *(const short8v*)(sa + ((size_t)(kt * 4 + (lane >> 4)) * 16 + (lane & 15)) * 8);
#pragma unroll
  for (int ns = 0; ns < 4; ++ns) {
    const int ntile = blockIdx.y * 16 + w * 4 + ns;
    const unsigned short* wb = Wip + (((size_t)(dir * 4 + layer) * 512 + ntile * 8) * 64 + lane) * 8;
    f32x4 acc = (f32x4){0.f, 0.f, 0.f, 0.f};
#pragma unroll
    for (int kt = 0; kt < 8; ++kt) {
      short8v bf = *(const short8v*)(wb + (size_t)kt * 64 * 8);
      acc = __builtin_amdgcn_mfma_f32_16x16x32_bf16(af[kt], bf, acc, 0, 0, 0);
    }
#pragma unroll
    for (int r = 0; r < 4; ++r)
      xz[(size_t)(tok0 + (lane >> 4) * 4 + r) * 1024 + ntile * 16 + (lane & 15)] = f2bf(acc[r]);
  }
}

// ---------------------------------------------------------------------------
// xprojf_k: FUSED causal-conv4+silu + x_proj MFMA GEMM. xz BF16.
// ---------------------------------------------------------------------------
__global__ __launch_bounds__(256) void xprojf_k(
    const unsigned short* __restrict__ xzF, const unsigned short* __restrict__ xzR,
    const float* __restrict__ cwF, const float* __restrict__ cwR,
    const float* __restrict__ cbF, const float* __restrict__ cbR,
    const unsigned short* __restrict__ Wxp, int layer,
    float* __restrict__ xcF, float* __restrict__ xcR,
    float* __restrict__ dbF, float* __restrict__ dbR)
{
  const int dir = blockIdx.z;
  const unsigned short* xz = dir ? xzR : xzF;
  const float* cw = dir ? cwR : cwF;
  const float* cb = dir ? cbR : cbF;
  float* xc = dir ? xcR : xcF;
  float* db = dir ? dbR : dbF;
  __shared__ unsigned short sa[64 * 16 * 8];   // 16KB
  const int t = threadIdx.x;
  const int tok0 = blockIdx.x * 16;

#pragma unroll
  for (int ii = 0; ii < 4; ++ii) {
    int idx = ii * 256 + t;
    int tk = idx >> 6, tok = tok0 + tk;
    int e0 = (idx & 63) << 3;
    int l = tok & 127;
    const unsigned short* col = xz + (size_t)tok * 1024 + e0;

    unsigned short v3[8] = {}, v2[8] = {}, v1[8] = {}, v0[8];
    if (l >= 3) *(uint4*)v3 = *(const uint4*)(col - 3 * 1024);
    if (l >= 2) *(uint4*)v2 = *(const uint4*)(col - 2 * 1024);
    if (l >= 1) *(uint4*)v1 = *(const uint4*)(col - 1 * 1024);
    *(uint4*)v0 = *(const uint4*)col;

    float cbv[8];
    *(float4*)cbv = *(const float4*)(cb + e0); *(float4*)(cbv+4) = *(const float4*)(cb + e0 + 4);

    float res[8];
#pragma unroll
    for (int j = 0; j < 8; ++j) {
      float4 cv = ((const float4*)cw)[e0 + j];
      float a = cbv[j];
      a = fmaf(cv.x, bf2f(v3[j]), a);
      a = fmaf(cv.y, bf2f(v2[j]), a);
      a = fmaf(cv.z, bf2f(v1[j]), a);
      a = fmaf(cv.w, bf2f(v0[j]), a);
      res[j] = a / (1.f + __expf(-a));
    }
    float4 r0 = {res[0], res[1], res[2], res[3]};
    float4 r1 = {res[4], res[5], res[6], res[7]};
    float* xcp = xc + (size_t)tok * EDIM + e0;
    *(float4*)xcp = r0; *(float4*)(xcp + 4) = r1;

    unsigned ub[4];
#pragma unroll
    for (int p = 0; p < 4; ++p)
      ub[p] = (unsigned)f2bf(res[2*p]) | ((unsigned)f2bf(res[2*p+1]) << 16);
    int c = (e0 >> 3) * 16 + tk;
    c ^= (c >> 4) & 15;
    uint4 w4 = {ub[0], ub[1], ub[2], ub[3]};
    *(uint4*)(sa + (size_t)c * 8) = w4;
  }
  __syncthreads();

  const int w = t >> 6, lane = t & 63;
  if (w < 3) {
    const int nt = w;
    const unsigned short* wbase = Wxp + ((size_t)(dir * 4 + layer) * 3 * 16 * 64) * 8;
    f32x4 acc = (f32x4){0.f, 0.f, 0.f, 0.f};
#pragma unroll
    for (int kt = 0; kt < 16; ++kt) {
      int c = (kt * 4 + (lane >> 4)) * 16 + (lane & 15);
      c ^= (c >> 4) & 15;
      short8v af = *(const short8v*)(sa + (size_t)c * 8);
      short8v bf = *(const short8v*)(wbase + ((size_t)(nt * 16 + kt) * 64 + lane) * 8);
      acc = __builtin_amdgcn_mfma_f32_16x16x32_bf16(af, bf, acc, 0, 0, 0);
    }
#pragma unroll
    for (int r = 0; r < 4; ++r)
      db[(size_t)(tok0 + (lane >> 4) * 4 + r) * 48 + nt * 16 + (lane & 15)] = acc[r];
  }
}

// ---------------------------------------------------------------------------
// scan4_k: selective scan + gating; z read from BF16 xz.
// ---------------------------------------------------------------------------
__global__ __launch_bounds__(256) void scan4_k(
    const unsigned short* __restrict__ xzF, const unsigned short* __restrict__ xzR,
    const float* __restrict__ xcF, const float* __restrict__ xcR,
    const float* __restrict__ dbF, const float* __restrict__ dbR,
    const float* __restrict__ dwF, const float* __restrict__ dwR,
    const float* __restrict__ dtbF, const float* __restrict__ dtbR,
    const float* __restrict__ AlF, const float* __restrict__ AlR,
    const float* __restrict__ DpF, const float* __restrict__ DpR,
    unsigned short* __restrict__ yoF, unsigned short* __restrict__ yoR)
{
  const int dir = blockIdx.z;
  const unsigned short* xz = dir ? xzR : xzF;
  const float* xc = dir ? xcR : xcF;
  const float* db = dir ? dbR : dbF;
  const float* dw = dir ? dwR : dwF;
  const float* dtbv = dir ? dtbR : dtbF;
  const float* Al = dir ? AlR : AlF;
  const float* Dp = dir ? DpR : DpF;
  unsigned short* yo = dir ? yoR : yoF;

  __shared__ float sdb[FRAMES * 48];
  __shared__ float sxc[FRAMES * 16];
  __shared__ float sgz[FRAMES * 16];
  __shared__ float sdl[FRAMES * 16];
  const int b = blockIdx.x >> 5;
  const int e0 = (blockIdx.x & 31) << 4;
  const int t = threadIdx.x, g = t >> 4, n = t & 15;
  const int e = e0 + g;

  const float* dbp = db + (size_t)b * FRAMES * 48;
  for (int i = t; i < FRAMES * 48 / 4; i += 256)
    ((float4*)sdb)[i] = ((const float4*)dbp)[i];
  for (int i = t; i < FRAMES * 16; i += 256) {
    int l = i >> 4, c = i & 15;
    int ee = e0 + c;
    sxc[i] = xc[(size_t)(b * FRAMES + l) * EDIM + ee];
    float zz = bf2f(xz[(size_t)(b * FRAMES + l) * 1024 + 512 + ee]);
    sgz[i] = zz / (1.f + __expf(-zz));
    const float* d = db + (size_t)(b * FRAMES + l) * 48;
    const float* w = dw + (size_t)ee * 16;
    float a = dtbv[ee];
#pragma unroll
    for (int q = 0; q < 4; ++q) {
      float4 dv = *(const float4*)(d + 4 * q);
      float4 wv = *(const float4*)(w + 4 * q);
      a = fmaf(dv.x, wv.x, a); a = fmaf(dv.y, wv.y, a);
      a = fmaf(dv.z, wv.z, a); a = fmaf(dv.w, wv.w, a);
    }
    sdl[i] = (a > 20.f) ? a : __logf(1.f + __expf(a));
  }
  float An = -expf(Al[e * NSTATE + n]);
  float Dv = Dp[e];
  float h = 0.f;
  unsigned short* yp = yo + ((size_t)((e >> 5) * 4 + ((e >> 3) & 3)) * 1024 + b * FRAMES) * 8 + (e & 7);
  __syncthreads();

#pragma unroll 1
  for (int l = 0; l < FRAMES; ++l) {
    float dlt = sdl[l * 16 + g];
    float xcv = sxc[l * 16 + g];
    float Bn = sdb[l * 48 + 16 + n];
    float Cn = sdb[l * 48 + 32 + n];
    float dA = __expf(dlt * An);
    h = fmaf(dA, h, dlt * xcv * Bn);
    float part = h * Cn;
    part += __shfl_xor(part, 1, 16);
    part += __shfl_xor(part, 2, 16);
    part += __shfl_xor(part, 4, 16);
    part += __shfl_xor(part, 8, 16);
    if (n == 0) {
      float a2 = fmaf(Dv, xcv, part);
      yp[(size_t)l * 8] = f2bf(a2 * sgz[l * 16 + g]);
    }
  }
}

// ---------------------------------------------------------------------------
// outproj_mfma: zero-LDS bf16 MFMA GEMM + residual add.
// ---------------------------------------------------------------------------
__global__ __launch_bounds__(256) void outproj_mfma(
    const unsigned short* __restrict__ yoF, const unsigned short* __restrict__ yoR,
    const unsigned short* __restrict__ Wop, int layer,
    float* __restrict__ xF, float* __restrict__ xR)
{
  const int dir = blockIdx.z;
  const unsigned short* yo = dir ? yoR : yoF;
  float* xx = dir ? xR : xF;
  const int t = threadIdx.x, lane = t & 63, w = t >> 6;
  const int m0 = blockIdx.x * 32, n0 = blockIdx.y * 64;
  const int ntile = blockIdx.y * 4 + w;
  const unsigned short* wb = Wop + (((size_t)(dir * 4 + layer) * 256 + ntile * 16) * 64 + lane) * 8;
  f32x4 acc[2];
  acc[0] = (f32x4){0.f, 0.f, 0.f, 0.f};
  acc[1] = (f32x4){0.f, 0.f, 0.f, 0.f};
#pragma unroll
  for (int kt = 0; kt < 16; ++kt) {
    short8v bf = *(const short8v*)(wb + (size_t)kt * 64 * 8);
#pragma unroll
    for (int mt = 0; mt < 2; ++mt) {
      short8v af = *(const short8v*)(yo + ((size_t)(kt * 4 + (lane >> 4)) * 1024 + m0 + mt * 16 + (lane & 15)) * 8);
      acc[mt] = __builtin_amdgcn_mfma_f32_16x16x32_bf16(af, bf, acc[mt], 0, 0, 0);
    }
  }
#pragma unroll
  for (int mt = 0; mt < 2; ++mt)
#pragma unroll
    for (int r = 0; r < 4; ++r) {
      size_t ci = (size_t)(m0 + mt * 16 + (lane >> 4) * 4 + r) * DD + n0 + w * 16 + (lane & 15);
      xx[ci] += acc[mt][r];
    }
}

__global__ __launch_bounds__(256) void head_k(
    const float* __restrict__ xf, const float* __restrict__ xr,
    const float* __restrict__ fcw, const float* __restrict__ fcb,
    const float* __restrict__ fc2w, const float* __restrict__ fc2b,
    float* __restrict__ out)
{
  int b = blockIdx.x;
  __shared__ float xl[2 * DD];
  __shared__ float h[DD];
  __shared__ float hp[4];
  int t = threadIdx.x;
  xl[t]      = xf[(size_t)(b * FRAMES + FRAMES - 1) * DD + t];
  xl[DD + t] = xr[(size_t)(b * FRAMES + 0) * DD + t];
  __syncthreads();
  float acc = fcb[t];
  for (int k = 0; k < 2 * DD; ++k) acc = fmaf(xl[k], fcw[(size_t)t * 2 * DD + k], acc);
  h[t] = acc;
  __syncthreads();
  {
    int c = t >> 7, k = t & 127;
    float p = h[k] * fc2w[c * DD + k] + h[k + 128] * fc2w[c * DD + k + 128];
#pragma unroll
    for (int off = 32; off; off >>= 1) p += __shfl_xor(p, off, 64);
    if ((t & 63) == 0) hp[t >> 6] = p;
  }
  __syncthreads();
  if (t < 2) out[b * 2 + t] = hp[2 * t] + hp[2 * t + 1] + fc2b[t];
}

// ---------------------------------------------------------------------------
extern "C" void kernel_launch(void* const* d_in, const int* in_sizes, int n_in,
                              void* d_out, int out_size, void* d_ws, size_t ws_size,
                              hipStream_t stream) {
  const float* video = (const float*)d_in[0];
  const float* audio = (const float*)d_in[1];
  const float* c1w = (const float*)d_in[2];
  const float* c1b = (const float*)d_in[3];
  const float* c2w = (const float*)d_in[4];
  const float* c2b = (const float*)d_in[5];
  const float* fcw = (const float*)d_in[6];
  const float* fcb = (const float*)d_in[7];
  const float* Wf[10]; const float* Wb_[10];
  for (int i = 0; i < 10; ++i) { Wf[i] = (const float*)d_in[8+i]; Wb_[i] = (const float*)d_in[18+i]; }
  const float* fc_w  = (const float*)d_in[28];
  const float* fc_b  = (const float*)d_in[29];
  const float* fc2_w = (const float*)d_in[30];
  const float* fc2_b = (const float*)d_in[31];
  float* out = (float*)d_out;

  // workspace (float slots; xz buffers bf16 in float-sized slots)
  float* ws   = (float*)d_ws;
  float* feat = ws;                       // 65536
  float* xf   = feat + 65536;             // 262144
  float* xr   = xf   + 262144;            // 262144
  unsigned short* xzF = (unsigned short*)(xr + 262144);
  unsigned short* xzR = (unsigned short*)(xr + 262144 + 1048576);
  float* xcF  = xr + 262144 + 2097152;    // 524288
  float* xcR  = xcF  + 524288;            // 524288
  float* dbF  = xcR  + 524288;            // 49152
  float* dbR  = dbF  + 49152;             // 49152
  unsigned short* yoF = (unsigned short*)(dbR + 49152);     // 524288 sh
  unsigned short* yoR = yoF + 524288;
  unsigned short* X1  = yoR + 524288;                        // 33554432 sh
  unsigned short* Wbp = X1 + 33554432;                       // 18432 sh
  unsigned short* Wip = Wbp + 18432;                         // 2097152 sh
  unsigned short* Wop = Wip + 2097152;                       // 1048576 sh
  unsigned short* Wxp = Wop + 1048576;                       // 196608 sh
  unsigned short* Wb1 = Wxp + 196608;                        // 1024 sh

  // 1. single pack + CNN
  hipMemsetAsync(feat, 0, (size_t)TOK * 64 * sizeof(float), stream);
  pack_all<<<dim3(1642), 256, 0, stream>>>(Wf[1], Wb_[1], Wf[9], Wb_[9], Wf[4], Wb_[4],
                                           c2w, c1w, Wip, Wop, Wxp, Wbp, Wb1);
  conv1_mfma<<<dim3(TOK), 256, 0, stream>>>(video, Wb1, c1b, X1);
  conv2_k<<<dim3(TOK * 2), 256, 0, stream>>>(X1, Wbp, c2b, feat);

  // 2. cnn fc (writes xf+xr directly; audio cols fused)
  fcgemm_k<<<dim3(16, 4), 256, 0, stream>>>(feat, fcw, fcb, audio, xf, xr);

  // 3. bi-Mamba (4 kernels per layer)
  for (int l = 0; l < NLAYER; ++l) {
    const float* nwF  = Wf[0] + l*DD;              const float* nwR  = Wb_[0] + l*DD;
    const float* cwF_ = Wf[2] + l*EDIM*4;          const float* cwR_ = Wb_[2] + l*EDIM*4;
    const float* cbF_ = Wf[3] + l*EDIM;            const float* cbR_ = Wb_[3] + l*EDIM;
    const float* dwF  = Wf[5] + l*EDIM*DTRANK;     const float* dwR  = Wb_[5] + l*EDIM*DTRANK;
    const float* dtbF = Wf[6] + l*EDIM;            const float* dtbR = Wb_[6] + l*EDIM;
    const float* AlF  = Wf[7] + l*EDIM*NSTATE;     const float* AlR  = Wb_[7] + l*EDIM*NSTATE;
    const float* DpF  = Wf[8] + l*EDIM;            const float* DpR  = Wb_[8] + l*EDIM;

    inproj_mfma3<<<dim3(64, 4, 2), 256, 0, stream>>>(xf, xr, nwF, nwR, Wip, l, xzF, xzR);
    xprojf_k<<<dim3(64, 1, 2), 256, 0, stream>>>(xzF, xzR, cwF_, cwR_, cbF_, cbR_,
                                                 Wxp, l, xcF, xcR, dbF, dbR);
    scan4_k<<<dim3(256, 1, 2), 256, 0, stream>>>(xzF, xzR, xcF, xcR, dbF, dbR, dwF, dwR,
                                                 dtbF, dtbR, AlF, AlR, DpF, DpR, yoF, yoR);
    outproj_mfma<<<dim3(32, 4, 2), 256, 0, stream>>>(yoF, yoR, Wop, l, xf, xr);
  }

  // 4. head
  head_k<<<dim3(BATCH), 256, 0, stream>>>(xf, xr, fc_w, fc_b, fc2_w, fc2_b, out);
}

// Round 19
// 349.300 us; speedup vs baseline: 1.1431x; 1.1431x over previous
//
#include <hip/hip_runtime.h>
#include <hip/hip_bf16.h>
#include <cstdint>
#include <cstddef>

#define BATCH 8
#define FRAMES 128
#define TOK (BATCH*FRAMES)   // 1024
#define NM 60
#define VF 196
#define DD 256
#define EDIM 512
#define NSTATE 16
#define DTRANK 16
#define NLAYER 4

typedef __attribute__((ext_vector_type(8))) short short8v;
typedef __attribute__((ext_vector_type(4))) float f32x4;

__device__ __forceinline__ unsigned short f2bf(float f) {
  unsigned x = __float_as_uint(f);
  unsigned r = (x + 0x7FFFu + ((x >> 16) & 1u)) >> 16;
  return (unsigned short)r;
}
__device__ __forceinline__ float bf2f(unsigned short u) {
  return __uint_as_float((unsigned)u << 16);
}

// ---------------------------------------------------------------------------
// pack_all: mamba weights + conv weights -> bf16 MFMA fragment order.
// ---------------------------------------------------------------------------
__global__ void pack_all(const float* __restrict__ ipF, const float* __restrict__ ipR,
                         const float* __restrict__ opF, const float* __restrict__ opR,
                         const float* __restrict__ xpF, const float* __restrict__ xpR,
                         const float* __restrict__ w2, const float* __restrict__ w1,
                         unsigned short* __restrict__ Wip, unsigned short* __restrict__ Wop,
                         unsigned short* __restrict__ Wxp, unsigned short* __restrict__ Wb,
                         unsigned short* __restrict__ Wb1) {
  int id = blockIdx.x * 256 + threadIdx.x;
  if (id < 262144) {                     // in_proj
    int dl = id >> 15, r = id & 32767;
    int ntile = r >> 9, kt = (r >> 6) & 7, lane = r & 63;
    int dir = dl >> 2, layer = dl & 3;
    const float* src = (dir ? ipR : ipF) + (size_t)layer * 1024 * 256
                       + (size_t)(ntile * 16 + (lane & 15)) * 256 + kt * 32 + (lane >> 4) * 8;
    unsigned u[4];
#pragma unroll
    for (int p = 0; p < 4; ++p)
      u[p] = (unsigned)f2bf(src[2 * p]) | ((unsigned)f2bf(src[2 * p + 1]) << 16);
    uint4 v = {u[0], u[1], u[2], u[3]};
    *(uint4*)(Wip + (size_t)id * 8) = v;
  } else if (id < 262144 + 131072) {     // out_proj
    int id2 = id - 262144;
    int dl = id2 >> 14, rr = id2 & 16383;
    int ntile = rr >> 10, kt = (rr >> 6) & 15, lane = rr & 63;
    int dir = dl >> 2, layer = dl & 3;
    const float* src = (dir ? opR : opF) + (size_t)layer * 256 * 512
                       + (size_t)(ntile * 16 + (lane & 15)) * 512 + kt * 32 + (lane >> 4) * 8;
    unsigned u[4];
#pragma unroll
    for (int p = 0; p < 4; ++p)
      u[p] = (unsigned)f2bf(src[2 * p]) | ((unsigned)f2bf(src[2 * p + 1]) << 16);
    uint4 v = {u[0], u[1], u[2], u[3]};
    *(uint4*)(Wop + (size_t)id2 * 8) = v;
  } else if (id < 262144 + 131072 + 24576) {  // x_proj (48 x 512)
    int id3 = id - 262144 - 131072;
    int dl = id3 / 3072, rr = id3 % 3072;
    int ntile = rr >> 10, kt = (rr >> 6) & 15, lane = rr & 63;
    int dir = dl >> 2, layer = dl & 3;
    const float* src = (dir ? xpR : xpF) + (size_t)layer * 48 * 512
                       + (size_t)(ntile * 16 + (lane & 15)) * 512 + kt * 32 + (lane >> 4) * 8;
    unsigned u[4];
#pragma unroll
    for (int p = 0; p < 4; ++p)
      u[p] = (unsigned)f2bf(src[2 * p]) | ((unsigned)f2bf(src[2 * p + 1]) << 16);
    uint4 v = {u[0], u[1], u[2], u[3]};
    *(uint4*)(Wxp + (size_t)id3 * 8) = v;
  } else if (id < 417792 + 2304) {       // w2 conv2 A-frags
    int id4 = id - 417792;
    int lane = id4 & 63;
    int mt = (id4 >> 6) & 3;
    int sh = id4 >> 8;
    int dy = sh / 3, dx = sh % 3;
    int oc = mt * 16 + (lane & 15);
    int ic0 = (lane >> 4) * 8;
    unsigned u[4];
#pragma unroll
    for (int p = 0; p < 4; ++p) {
      unsigned short lo = f2bf(w2[((oc * 32 + ic0 + 2 * p) * 3 + dy) * 3 + dx]);
      unsigned short hi = f2bf(w2[((oc * 32 + ic0 + 2 * p + 1) * 3 + dy) * 3 + dx]);
      u[p] = (unsigned)lo | ((unsigned)hi << 16);
    }
    uint4 v = {u[0], u[1], u[2], u[3]};
    *(uint4*)(Wb + (size_t)id4 * 8) = v;
  } else if (id < 417792 + 2304 + 128) { // w1 conv1 A-frags (K=32, k>=27 zero)
    int id5 = id - 417792 - 2304;
    int mt = id5 >> 6, lane = id5 & 63;
    int oc = mt * 16 + (lane & 15);
    int ko = lane >> 4;
    unsigned u[4];
#pragma unroll
    for (int p = 0; p < 4; ++p) {
      int k0 = ko * 8 + 2 * p, k1 = k0 + 1;
      unsigned short lo = (k0 < 27) ? f2bf(w1[oc * 27 + k0]) : 0;
      unsigned short hi = (k1 < 27) ? f2bf(w1[oc * 27 + k1]) : 0;
      u[p] = (unsigned)lo | ((unsigned)hi << 16);
    }
    uint4 v = {u[0], u[1], u[2], u[3]};
    *(uint4*)(Wb1 + (size_t)id5 * 8) = v;
  }
}

// ---------------------------------------------------------------------------
// conv1_mfma: conv(3->32,3x3,SAME)+bias+relu+maxpool2 via K=32 MFMA.
// C1ICS padded 4488->4496 u16 (ic-plane octet bank ranges separated).
// ---------------------------------------------------------------------------
#define C1RS 68
#define C1ICS 4496
__global__ __launch_bounds__(256) void conv1_mfma(
    const float* __restrict__ video, const unsigned short* __restrict__ Wb1,
    const float* __restrict__ b1, unsigned short* __restrict__ X1)
{
  __shared__ unsigned short ldsu[3 * C1ICS + 96];
  const int img = blockIdx.x, t = threadIdx.x;
  const float* vin = video + (size_t)img * 12288;
  const int lane = t & 63, wv = t >> 6;
  const int col = lane & 15, ko = lane >> 4;

  for (int i = t; i < (3 * C1ICS + 96) / 2; i += 256) ((unsigned*)ldsu)[i] = 0;
  __syncthreads();
#pragma unroll
  for (int i = 0; i < 12; ++i) {
    int c = i * 256 + t;
    int ic = c >> 10, rem = c & 1023, gy = rem >> 4, c4 = rem & 15;
    float4 v = *(const float4*)(vin + ic * 4096 + gy * 64 + c4 * 4);
    unsigned lo = (unsigned)f2bf(v.x) | ((unsigned)f2bf(v.y) << 16);
    unsigned hi = (unsigned)f2bf(v.z) | ((unsigned)f2bf(v.w) << 16);
    int di = ic * C1ICS + (gy + 1) * C1RS + 4 + c4 * 4;
    *(uint2*)(ldsu + di) = (uint2){lo, hi};
  }

  short8v A0 = *(const short8v*)(Wb1 + (size_t)(0 * 64 + lane) * 8);
  short8v A1 = *(const short8v*)(Wb1 + (size_t)(1 * 64 + lane) * 8);
  float bia[2][4];
#pragma unroll
  for (int mt = 0; mt < 2; ++mt)
#pragma unroll
    for (int r = 0; r < 4; ++r) bia[mt][r] = b1[mt * 16 + ko * 4 + r];

  int offs[8];
#pragma unroll
  for (int j = 0; j < 8; ++j) {
    int k = ko * 8 + j;
    int o = 0;
    if (k < 27) {
      int ic = k / 9, tap = k - ic * 9;
      int dy = tap / 3, dx = tap - dy * 3;
      o = ic * C1ICS + dy * C1RS + dx + 3;
    }
    offs[j] = o;
  }
  __syncthreads();

  f32x4 z4 = {0.f, 0.f, 0.f, 0.f};
#pragma unroll 1
  for (int rp = 0; rp < 8; ++rp) {
    const int y0 = wv * 16 + rp * 2;
#pragma unroll
    for (int xg = 0; xg < 4; ++xg) {
      const int bse = y0 * C1RS + xg * 16 + col;
      short8v vb0, vb1;
#pragma unroll
      for (int j = 0; j < 8; ++j) {
        vb0[j] = (short)ldsu[bse + offs[j]];
        vb1[j] = (short)ldsu[bse + C1RS + offs[j]];
      }
      f32x4 c00 = __builtin_amdgcn_mfma_f32_16x16x32_bf16(A0, vb0, z4, 0, 0, 0);
      f32x4 c10 = __builtin_amdgcn_mfma_f32_16x16x32_bf16(A1, vb0, z4, 0, 0, 0);
      f32x4 c01 = __builtin_amdgcn_mfma_f32_16x16x32_bf16(A0, vb1, z4, 0, 0, 0);
      f32x4 c11 = __builtin_amdgcn_mfma_f32_16x16x32_bf16(A1, vb1, z4, 0, 0, 0);
      const int py = wv * 8 + rp;
      const int pxp = xg * 8 + (col >> 1);
#pragma unroll
      for (int mt = 0; mt < 2; ++mt) {
        f32x4 ca = mt ? c10 : c00;
        f32x4 cb = mt ? c11 : c01;
        unsigned pk[2];
#pragma unroll
        for (int r = 0; r < 4; ++r) {
          float va = fmaxf(ca[r] + bia[mt][r], 0.f);
          float vb = fmaxf(cb[r] + bia[mt][r], 0.f);
          float v = fmaxf(va, vb);
          v = fmaxf(v, __shfl_xor(v, 1, 64));
          unsigned short u = f2bf(v);
          if ((r & 1) == 0) pk[r >> 1] = (unsigned)u;
          else              pk[r >> 1] |= ((unsigned)u << 16);
        }
        if ((col & 1) == 0) {
          uint2 o = {pk[0], pk[1]};
          *(uint2*)(X1 + ((size_t)(img * 1024 + py * 32 + pxp) * 32 + mt * 16 + ko * 4)) = o;
        }
      }
    }
  }
}

// ---------------------------------------------------------------------------
// conv2_k: R17 CHAMPION FORM (do not modify — R11/R12/R18 variants all
// regressed). Full-image, q-split acc[4][2] (VGPR 128 = 16-wave tier),
// OCT_STRIDE +32B pad, direct feat write.
// ---------------------------------------------------------------------------
#define OCT_STRIDE  (1156 * 16 + 32)
#define X_LDS_BYTES (4 * OCT_STRIDE)
__global__ __launch_bounds__(256) void conv2_k(
    const unsigned short* __restrict__ X1, const unsigned short* __restrict__ Wb,
    const float* __restrict__ b2, float* __restrict__ feat)
{
  extern __shared__ char sm[];
  float* part = (float*)(sm + X_LDS_BYTES);
  const int img = blockIdx.x, t = threadIdx.x;
  const int lane = t & 63, wv = t >> 6;
  const int kg = lane >> 4, l15 = lane & 15;

  for (int j = t; j < 1156; j += 256) {
    int r = j / 34, cc = j - r * 34;
    if (r == 0 || r == 33 || cc == 0 || cc == 33) {
      uint4 z = {0, 0, 0, 0};
#pragma unroll
      for (int oct = 0; oct < 4; ++oct)
        *(uint4*)(sm + oct * OCT_STRIDE + j * 16) = z;
    }
  }
  const uint4* src = (const uint4*)(X1 + (size_t)img * 32768);
#pragma unroll 4
  for (int i = 0; i < 16; ++i) {
    int c = i * 256 + t;
    uint4 v = src[c];
    int oct = c & 3, P = c >> 2;
    int y = P >> 5, x = P & 31;
    *(uint4*)(sm + oct * OCT_STRIDE + ((y + 1) * 34 + (x + 1)) * 16) = v;
  }
  __syncthreads();

  float bia[4][4];
#pragma unroll
  for (int mt = 0; mt < 4; ++mt)
#pragma unroll
    for (int r = 0; r < 4; ++r) bia[mt][r] = b2[mt * 16 + kg * 4 + r];

  float msum[4][4];
#pragma unroll
  for (int mt = 0; mt < 4; ++mt)
#pragma unroll
    for (int r = 0; r < 4; ++r) msum[mt][r] = 0.f;

#pragma unroll 1
  for (int pass = 0; pass < 2; ++pass) {
#pragma unroll 1
    for (int hf = 0; hf < 2; ++hf) {
#pragma unroll 1
      for (int qq = 0; qq < 2; ++qq) {           // pool pair {qq, qq+2}
        f32x4 acc[4][2];
#pragma unroll
        for (int mt = 0; mt < 4; ++mt) {
          acc[mt][0] = (f32x4){0.f, 0.f, 0.f, 0.f};
          acc[mt][1] = (f32x4){0.f, 0.f, 0.f, 0.f};
        }
        int Pq[2];
#pragma unroll
        for (int j = 0; j < 2; ++j) {
          int qsel = qq + j * 2;
          int p = (wv * 16 + pass * 8 + hf * 4 + qsel) * 16 + l15;
          int y = p >> 5, x = p & 31;
          Pq[j] = y * 34 + x;
        }
#pragma unroll
        for (int sh = 0; sh < 9; ++sh) {
          const int dy = sh / 3, dx = sh % 3;
          const int shoff = (dy * 34 + dx) * 16;
          short8v Af[4];
#pragma unroll
          for (int mt = 0; mt < 4; ++mt)
            Af[mt] = *(const short8v*)(Wb + ((size_t)(sh * 4 + mt) * 64 + lane) * 8);
          short8v B0 = *(const short8v*)(sm + kg * OCT_STRIDE + Pq[0] * 16 + shoff);
          short8v B1 = *(const short8v*)(sm + kg * OCT_STRIDE + Pq[1] * 16 + shoff);
#pragma unroll
          for (int mt = 0; mt < 4; ++mt) {
            acc[mt][0] = __builtin_amdgcn_mfma_f32_16x16x32_bf16(Af[mt], B0, acc[mt][0], 0, 0, 0);
            acc[mt][1] = __builtin_amdgcn_mfma_f32_16x16x32_bf16(Af[mt], B1, acc[mt][1], 0, 0, 0);
          }
        }
#pragma unroll
        for (int mt = 0; mt < 4; ++mt)
#pragma unroll
          for (int r = 0; r < 4; ++r) {
            float va = fmaxf(acc[mt][0][r] + bia[mt][r], 0.f);
            float vb = fmaxf(acc[mt][1][r] + bia[mt][r], 0.f);
            float v = fmaxf(va, vb);
            v = fmaxf(v, __shfl_xor(v, 1, 64));   // x-pair pool
            msum[mt][r] += v;                      // counted twice
          }
      }
    }
  }
#pragma unroll
  for (int mt = 0; mt < 4; ++mt)
#pragma unroll
    for (int r = 0; r < 4; ++r) {
      float v = msum[mt][r];
      v += __shfl_xor(v, 1, 64);
      v += __shfl_xor(v, 2, 64);
      v += __shfl_xor(v, 4, 64);
      v += __shfl_xor(v, 8, 64);
      if (l15 == 0) part[wv * 64 + mt * 16 + kg * 4 + r] = v * 0.5f;
    }
  __syncthreads();
  if (t < 64)
    feat[(size_t)img * 64 + t] =
        (part[t] + part[64 + t] + part[128 + t] + part[192 + t]) * (1.f / 256.f);
}

// ---------------------------------------------------------------------------
// fcgemm_k: feat @ fcw^T + fcb -> xf / reversed xr; audio cols fused.
// ---------------------------------------------------------------------------
__global__ __launch_bounds__(256) void fcgemm_k(
    const float* __restrict__ A, const float* __restrict__ B,
    const float* __restrict__ bias, const float* __restrict__ audio,
    float* __restrict__ xf, float* __restrict__ xr)
{
  __shared__ float sA[16][68];
  __shared__ float sB[16][68];
  const int t = threadIdx.x;
  const int m0 = blockIdx.x * 64;
  const int n0 = blockIdx.y * 64;
  const int tx = t & 15, ty = t >> 4;
  const int lk = t & 15, lr = t >> 4;
  float acc[4][4] = {};
  for (int k0 = 0; k0 < 64; k0 += 16) {
#pragma unroll
    for (int rr = 0; rr < 4; ++rr) {
      int m = m0 + lr + rr * 16;
      sA[lk][lr + rr * 16] = A[(size_t)m * 64 + k0 + lk];
      int n = n0 + lr + rr * 16;
      sB[lk][lr + rr * 16] = (n < VF) ? B[(size_t)n * 64 + k0 + lk] : 0.f;
    }
    __syncthreads();
#pragma unroll
    for (int kk = 0; kk < 16; ++kk) {
      float a0 = sA[kk][ty*4+0], a1 = sA[kk][ty*4+1], a2 = sA[kk][ty*4+2], a3 = sA[kk][ty*4+3];
      float b0 = sB[kk][tx*4+0], b1 = sB[kk][tx*4+1], b2 = sB[kk][tx*4+2], b3 = sB[kk][tx*4+3];
      acc[0][0]=fmaf(a0,b0,acc[0][0]); acc[0][1]=fmaf(a0,b1,acc[0][1]); acc[0][2]=fmaf(a0,b2,acc[0][2]); acc[0][3]=fmaf(a0,b3,acc[0][3]);
      acc[1][0]=fmaf(a1,b0,acc[1][0]); acc[1][1]=fmaf(a1,b1,acc[1][1]); acc[1][2]=fmaf(a1,b2,acc[1][2]); acc[1][3]=fmaf(a1,b3,acc[1][3]);
      acc[2][0]=fmaf(a2,b0,acc[2][0]); acc[2][1]=fmaf(a2,b1,acc[2][1]); acc[2][2]=fmaf(a2,b2,acc[2][2]); acc[2][3]=fmaf(a2,b3,acc[2][3]);
      acc[3][0]=fmaf(a3,b0,acc[3][0]); acc[3][1]=fmaf(a3,b1,acc[3][1]); acc[3][2]=fmaf(a3,b2,acc[3][2]); acc[3][3]=fmaf(a3,b3,acc[3][3]);
    }
    __syncthreads();
  }
#pragma unroll
  for (int i = 0; i < 4; ++i) {
    int m = m0 + ty * 4 + i;
    int b = m >> 7, l = m & 127;
    int mr = (b << 7) + (127 - l);
#pragma unroll
    for (int j = 0; j < 4; ++j) {
      int n = n0 + tx * 4 + j;
      float v;
      if (n < VF)       v = acc[i][j] + bias[n];
      else              v = audio[(size_t)b * (FRAMES * NM) + l * NM + (n - VF)];
      xf[(size_t)m * DD + n] = v;
      xr[(size_t)mr * DD + n] = v;
    }
  }
}

// ---------------------------------------------------------------------------
// inproj_mfma3: fused rmsnorm + bf16 MFMA GEMM. Writes xz as BF16.
// ---------------------------------------------------------------------------
__global__ __launch_bounds__(256) void inproj_mfma3(
    const float* __restrict__ xF, const float* __restrict__ xR,
    const float* __restrict__ nwF, const float* __restrict__ nwR,
    const unsigned short* __restrict__ Wip, int layer,
    unsigned short* __restrict__ xzF, unsigned short* __restrict__ xzR)
{
  const int dir = blockIdx.z;
  const float* x = dir ? xR : xF;
  const float* nw = dir ? nwR : nwF;
  unsigned short* xz = dir ? xzR : xzF;
  __shared__ unsigned short sa[32 * 16 * 8];   // 8KB
  const int t = threadIdx.x;
  const int tok0 = blockIdx.x * 16;
  {
    const int tk = t >> 4, l16 = t & 15;
    const float* row = x + (size_t)(tok0 + tk) * DD + l16 * 16;
    float v[16];
    float ss = 0.f;
#pragma unroll
    for (int i = 0; i < 4; ++i) {
      float4 f = ((const float4*)row)[i];
      v[4*i] = f.x; v[4*i+1] = f.y; v[4*i+2] = f.z; v[4*i+3] = f.w;
      ss += f.x*f.x + f.y*f.y + f.z*f.z + f.w*f.w;
    }
    ss += __shfl_xor(ss, 1, 16);
    ss += __shfl_xor(ss, 2, 16);
    ss += __shfl_xor(ss, 4, 16);
    ss += __shfl_xor(ss, 8, 16);
    float scale = rsqrtf(ss * (1.f / DD) + 1e-5f);
    const float* nwp = nw + l16 * 16;
#pragma unroll
    for (int hh = 0; hh < 2; ++hh) {
      unsigned ub[4];
#pragma unroll
      for (int p = 0; p < 4; ++p) {
        unsigned short lo = f2bf(v[hh*8 + 2*p]     * scale * nwp[hh*8 + 2*p]);
        unsigned short hi = f2bf(v[hh*8 + 2*p + 1] * scale * nwp[hh*8 + 2*p + 1]);
        ub[p] = (unsigned)lo | ((unsigned)hi << 16);
      }
      int k0 = l16 * 16 + hh * 8;
      int kt = k0 >> 5, oct = (k0 >> 3) & 3;
      uint4 w4 = {ub[0], ub[1], ub[2], ub[3]};
      *(uint4*)(sa + ((size_t)(kt * 4 + oct) * 16 + tk) * 8) = w4;
    }
  }
  __syncthreads();
  const int lane = t & 63, w = t >> 6;
  short8v af[8];
#pragma unroll
  for (int kt = 0; kt < 8; ++kt)
    af[kt] = *(const short8v*)(sa + ((size_t)(kt * 4 + (lane >> 4)) * 16 + (lane & 15)) * 8);
#pragma unroll
  for (int ns = 0; ns < 4; ++ns) {
    const int ntile = blockIdx.y * 16 + w * 4 + ns;
    const unsigned short* wb = Wip + (((size_t)(dir * 4 + layer) * 512 + ntile * 8) * 64 + lane) * 8;
    f32x4 acc = (f32x4){0.f, 0.f, 0.f, 0.f};
#pragma unroll
    for (int kt = 0; kt < 8; ++kt) {
      short8v bf = *(const short8v*)(wb + (size_t)kt * 64 * 8);
      acc = __builtin_amdgcn_mfma_f32_16x16x32_bf16(af[kt], bf, acc, 0, 0, 0);
    }
#pragma unroll
    for (int r = 0; r < 4; ++r)
      xz[(size_t)(tok0 + (lane >> 4) * 4 + r) * 1024 + ntile * 16 + (lane & 15)] = f2bf(acc[r]);
  }
}

// ---------------------------------------------------------------------------
// xprojf_k: FUSED causal-conv4+silu + x_proj MFMA GEMM. xz BF16.
// ---------------------------------------------------------------------------
__global__ __launch_bounds__(256) void xprojf_k(
    const unsigned short* __restrict__ xzF, const unsigned short* __restrict__ xzR,
    const float* __restrict__ cwF, const float* __restrict__ cwR,
    const float* __restrict__ cbF, const float* __restrict__ cbR,
    const unsigned short* __restrict__ Wxp, int layer,
    float* __restrict__ xcF, float* __restrict__ xcR,
    float* __restrict__ dbF, float* __restrict__ dbR)
{
  const int dir = blockIdx.z;
  const unsigned short* xz = dir ? xzR : xzF;
  const float* cw = dir ? cwR : cwF;
  const float* cb = dir ? cbR : cbF;
  float* xc = dir ? xcR : xcF;
  float* db = dir ? dbR : dbF;
  __shared__ unsigned short sa[64 * 16 * 8];   // 16KB
  const int t = threadIdx.x;
  const int tok0 = blockIdx.x * 16;

#pragma unroll
  for (int ii = 0; ii < 4; ++ii) {
    int idx = ii * 256 + t;
    int tk = idx >> 6, tok = tok0 + tk;
    int e0 = (idx & 63) << 3;
    int l = tok & 127;
    const unsigned short* col = xz + (size_t)tok * 1024 + e0;

    unsigned short v3[8] = {}, v2[8] = {}, v1[8] = {}, v0[8];
    if (l >= 3) *(uint4*)v3 = *(const uint4*)(col - 3 * 1024);
    if (l >= 2) *(uint4*)v2 = *(const uint4*)(col - 2 * 1024);
    if (l >= 1) *(uint4*)v1 = *(const uint4*)(col - 1 * 1024);
    *(uint4*)v0 = *(const uint4*)col;

    float cbv[8];
    *(float4*)cbv = *(const float4*)(cb + e0); *(float4*)(cbv+4) = *(const float4*)(cb + e0 + 4);

    float res[8];
#pragma unroll
    for (int j = 0; j < 8; ++j) {
      float4 cv = ((const float4*)cw)[e0 + j];
      float a = cbv[j];
      a = fmaf(cv.x, bf2f(v3[j]), a);
      a = fmaf(cv.y, bf2f(v2[j]), a);
      a = fmaf(cv.z, bf2f(v1[j]), a);
      a = fmaf(cv.w, bf2f(v0[j]), a);
      res[j] = a / (1.f + __expf(-a));
    }
    float4 r0 = {res[0], res[1], res[2], res[3]};
    float4 r1 = {res[4], res[5], res[6], res[7]};
    float* xcp = xc + (size_t)tok * EDIM + e0;
    *(float4*)xcp = r0; *(float4*)(xcp + 4) = r1;

    unsigned ub[4];
#pragma unroll
    for (int p = 0; p < 4; ++p)
      ub[p] = (unsigned)f2bf(res[2*p]) | ((unsigned)f2bf(res[2*p+1]) << 16);
    int c = (e0 >> 3) * 16 + tk;
    c ^= (c >> 4) & 15;
    uint4 w4 = {ub[0], ub[1], ub[2], ub[3]};
    *(uint4*)(sa + (size_t)c * 8) = w4;
  }
  __syncthreads();

  const int w = t >> 6, lane = t & 63;
  if (w < 3) {
    const int nt = w;
    const unsigned short* wbase = Wxp + ((size_t)(dir * 4 + layer) * 3 * 16 * 64) * 8;
    f32x4 acc = (f32x4){0.f, 0.f, 0.f, 0.f};
#pragma unroll
    for (int kt = 0; kt < 16; ++kt) {
      int c = (kt * 4 + (lane >> 4)) * 16 + (lane & 15);
      c ^= (c >> 4) & 15;
      short8v af = *(const short8v*)(sa + (size_t)c * 8);
      short8v bf = *(const short8v*)(wbase + ((size_t)(nt * 16 + kt) * 64 + lane) * 8);
      acc = __builtin_amdgcn_mfma_f32_16x16x32_bf16(af, bf, acc, 0, 0, 0);
    }
#pragma unroll
    for (int r = 0; r < 4; ++r)
      db[(size_t)(tok0 + (lane >> 4) * 4 + r) * 48 + nt * 16 + (lane & 15)] = acc[r];
  }
}

// ---------------------------------------------------------------------------
// scan4_k: selective scan + gating; z read from BF16 xz.
// ---------------------------------------------------------------------------
__global__ __launch_bounds__(256) void scan4_k(
    const unsigned short* __restrict__ xzF, const unsigned short* __restrict__ xzR,
    const float* __restrict__ xcF, const float* __restrict__ xcR,
    const float* __restrict__ dbF, const float* __restrict__ dbR,
    const float* __restrict__ dwF, const float* __restrict__ dwR,
    const float* __restrict__ dtbF, const float* __restrict__ dtbR,
    const float* __restrict__ AlF, const float* __restrict__ AlR,
    const float* __restrict__ DpF, const float* __restrict__ DpR,
    unsigned short* __restrict__ yoF, unsigned short* __restrict__ yoR)
{
  const int dir = blockIdx.z;
  const unsigned short* xz = dir ? xzR : xzF;
  const float* xc = dir ? xcR : xcF;
  const float* db = dir ? dbR : dbF;
  const float* dw = dir ? dwR : dwF;
  const float* dtbv = dir ? dtbR : dtbF;
  const float* Al = dir ? AlR : AlF;
  const float* Dp = dir ? DpR : DpF;
  unsigned short* yo = dir ? yoR : yoF;

  __shared__ float sdb[FRAMES * 48];
  __shared__ float sxc[FRAMES * 16];
  __shared__ float sgz[FRAMES * 16];
  __shared__ float sdl[FRAMES * 16];
  const int b = blockIdx.x >> 5;
  const int e0 = (blockIdx.x & 31) << 4;
  const int t = threadIdx.x, g = t >> 4, n = t & 15;
  const int e = e0 + g;

  const float* dbp = db + (size_t)b * FRAMES * 48;
  for (int i = t; i < FRAMES * 48 / 4; i += 256)
    ((float4*)sdb)[i] = ((const float4*)dbp)[i];
  for (int i = t; i < FRAMES * 16; i += 256) {
    int l = i >> 4, c = i & 15;
    int ee = e0 + c;
    sxc[i] = xc[(size_t)(b * FRAMES + l) * EDIM + ee];
    float zz = bf2f(xz[(size_t)(b * FRAMES + l) * 1024 + 512 + ee]);
    sgz[i] = zz / (1.f + __expf(-zz));
    const float* d = db + (size_t)(b * FRAMES + l) * 48;
    const float* w = dw + (size_t)ee * 16;
    float a = dtbv[ee];
#pragma unroll
    for (int q = 0; q < 4; ++q) {
      float4 dv = *(const float4*)(d + 4 * q);
      float4 wv = *(const float4*)(w + 4 * q);
      a = fmaf(dv.x, wv.x, a); a = fmaf(dv.y, wv.y, a);
      a = fmaf(dv.z, wv.z, a); a = fmaf(dv.w, wv.w, a);
    }
    sdl[i] = (a > 20.f) ? a : __logf(1.f + __expf(a));
  }
  float An = -expf(Al[e * NSTATE + n]);
  float Dv = Dp[e];
  float h = 0.f;
  unsigned short* yp = yo + ((size_t)((e >> 5) * 4 + ((e >> 3) & 3)) * 1024 + b * FRAMES) * 8 + (e & 7);
  __syncthreads();

#pragma unroll 1
  for (int l = 0; l < FRAMES; ++l) {
    float dlt = sdl[l * 16 + g];
    float xcv = sxc[l * 16 + g];
    float Bn = sdb[l * 48 + 16 + n];
    float Cn = sdb[l * 48 + 32 + n];
    float dA = __expf(dlt * An);
    h = fmaf(dA, h, dlt * xcv * Bn);
    float part = h * Cn;
    part += __shfl_xor(part, 1, 16);
    part += __shfl_xor(part, 2, 16);
    part += __shfl_xor(part, 4, 16);
    part += __shfl_xor(part, 8, 16);
    if (n == 0) {
      float a2 = fmaf(Dv, xcv, part);
      yp[(size_t)l * 8] = f2bf(a2 * sgz[l * 16 + g]);
    }
  }
}

// ---------------------------------------------------------------------------
// outproj_mfma: zero-LDS bf16 MFMA GEMM + residual add.
// ---------------------------------------------------------------------------
__global__ __launch_bounds__(256) void outproj_mfma(
    const unsigned short* __restrict__ yoF, const unsigned short* __restrict__ yoR,
    const unsigned short* __restrict__ Wop, int layer,
    float* __restrict__ xF, float* __restrict__ xR)
{
  const int dir = blockIdx.z;
  const unsigned short* yo = dir ? yoR : yoF;
  float* xx = dir ? xR : xF;
  const int t = threadIdx.x, lane = t & 63, w = t >> 6;
  const int m0 = blockIdx.x * 32, n0 = blockIdx.y * 64;
  const int ntile = blockIdx.y * 4 + w;
  const unsigned short* wb = Wop + (((size_t)(dir * 4 + layer) * 256 + ntile * 16) * 64 + lane) * 8;
  f32x4 acc[2];
  acc[0] = (f32x4){0.f, 0.f, 0.f, 0.f};
  acc[1] = (f32x4){0.f, 0.f, 0.f, 0.f};
#pragma unroll
  for (int kt = 0; kt < 16; ++kt) {
    short8v bf = *(const short8v*)(wb + (size_t)kt * 64 * 8);
#pragma unroll
    for (int mt = 0; mt < 2; ++mt) {
      short8v af = *(const short8v*)(yo + ((size_t)(kt * 4 + (lane >> 4)) * 1024 + m0 + mt * 16 + (lane & 15)) * 8);
      acc[mt] = __builtin_amdgcn_mfma_f32_16x16x32_bf16(af, bf, acc[mt], 0, 0, 0);
    }
  }
#pragma unroll
  for (int mt = 0; mt < 2; ++mt)
#pragma unroll
    for (int r = 0; r < 4; ++r) {
      size_t ci = (size_t)(m0 + mt * 16 + (lane >> 4) * 4 + r) * DD + n0 + w * 16 + (lane & 15);
      xx[ci] += acc[mt][r];
    }
}

__global__ __launch_bounds__(256) void head_k(
    const float* __restrict__ xf, const float* __restrict__ xr,
    const float* __restrict__ fcw, const float* __restrict__ fcb,
    const float* __restrict__ fc2w, const float* __restrict__ fc2b,
    float* __restrict__ out)
{
  int b = blockIdx.x;
  __shared__ float xl[2 * DD];
  __shared__ float h[DD];
  __shared__ float hp[4];
  int t = threadIdx.x;
  xl[t]      = xf[(size_t)(b * FRAMES + FRAMES - 1) * DD + t];
  xl[DD + t] = xr[(size_t)(b * FRAMES + 0) * DD + t];
  __syncthreads();
  float acc = fcb[t];
  for (int k = 0; k < 2 * DD; ++k) acc = fmaf(xl[k], fcw[(size_t)t * 2 * DD + k], acc);
  h[t] = acc;
  __syncthreads();
  {
    int c = t >> 7, k = t & 127;
    float p = h[k] * fc2w[c * DD + k] + h[k + 128] * fc2w[c * DD + k + 128];
#pragma unroll
    for (int off = 32; off; off >>= 1) p += __shfl_xor(p, off, 64);
    if ((t & 63) == 0) hp[t >> 6] = p;
  }
  __syncthreads();
  if (t < 2) out[b * 2 + t] = hp[2 * t] + hp[2 * t + 1] + fc2b[t];
}

// ---------------------------------------------------------------------------
extern "C" void kernel_launch(void* const* d_in, const int* in_sizes, int n_in,
                              void* d_out, int out_size, void* d_ws, size_t ws_size,
                              hipStream_t stream) {
  const float* video = (const float*)d_in[0];
  const float* audio = (const float*)d_in[1];
  const float* c1w = (const float*)d_in[2];
  const float* c1b = (const float*)d_in[3];
  const float* c2w = (const float*)d_in[4];
  const float* c2b = (const float*)d_in[5];
  const float* fcw = (const float*)d_in[6];
  const float* fcb = (const float*)d_in[7];
  const float* Wf[10]; const float* Wb_[10];
  for (int i = 0; i < 10; ++i) { Wf[i] = (const float*)d_in[8+i]; Wb_[i] = (const float*)d_in[18+i]; }
  const float* fc_w  = (const float*)d_in[28];
  const float* fc_b  = (const float*)d_in[29];
  const float* fc2_w = (const float*)d_in[30];
  const float* fc2_b = (const float*)d_in[31];
  float* out = (float*)d_out;

  // workspace (float slots; xz buffers bf16 in float-sized slots)
  float* ws   = (float*)d_ws;
  float* feat = ws;                       // 65536
  float* xf   = feat + 65536;             // 262144
  float* xr   = xf   + 262144;            // 262144
  unsigned short* xzF = (unsigned short*)(xr + 262144);
  unsigned short* xzR = (unsigned short*)(xr + 262144 + 1048576);
  float* xcF  = xr + 262144 + 2097152;    // 524288
  float* xcR  = xcF  + 524288;            // 524288
  float* dbF  = xcR  + 524288;            // 49152
  float* dbR  = dbF  + 49152;             // 49152
  unsigned short* yoF = (unsigned short*)(dbR + 49152);     // 524288 sh
  unsigned short* yoR = yoF + 524288;
  unsigned short* X1  = yoR + 524288;                        // 33554432 sh
  unsigned short* Wbp = X1 + 33554432;                       // 18432 sh
  unsigned short* Wip = Wbp + 18432;                         // 2097152 sh
  unsigned short* Wop = Wip + 2097152;                       // 1048576 sh
  unsigned short* Wxp = Wop + 1048576;                       // 196608 sh
  unsigned short* Wb1 = Wxp + 196608;                        // 1024 sh

  // 1. single pack + CNN
  pack_all<<<dim3(1642), 256, 0, stream>>>(Wf[1], Wb_[1], Wf[9], Wb_[9], Wf[4], Wb_[4],
                                           c2w, c1w, Wip, Wop, Wxp, Wbp, Wb1);
  conv1_mfma<<<dim3(TOK), 256, 0, stream>>>(video, Wb1, c1b, X1);
  conv2_k<<<dim3(TOK), 256, (size_t)(X_LDS_BYTES + 1024), stream>>>(X1, Wbp, c2b, feat);

  // 2. cnn fc (writes xf+xr directly; audio cols fused)
  fcgemm_k<<<dim3(16, 4), 256, 0, stream>>>(feat, fcw, fcb, audio, xf, xr);

  // 3. bi-Mamba (4 kernels per layer)
  for (int l = 0; l < NLAYER; ++l) {
    const float* nwF  = Wf[0] + l*DD;              const float* nwR  = Wb_[0] + l*DD;
    const float* cwF_ = Wf[2] + l*EDIM*4;          const float* cwR_ = Wb_[2] + l*EDIM*4;
    const float* cbF_ = Wf[3] + l*EDIM;            const float* cbR_ = Wb_[3] + l*EDIM;
    const float* dwF  = Wf[5] + l*EDIM*DTRANK;     const float* dwR  = Wb_[5] + l*EDIM*DTRANK;
    const float* dtbF = Wf[6] + l*EDIM;            const float* dtbR = Wb_[6] + l*EDIM;
    const float* AlF  = Wf[7] + l*EDIM*NSTATE;     const float* AlR  = Wb_[7] + l*EDIM*NSTATE;
    const float* DpF  = Wf[8] + l*EDIM;            const float* DpR  = Wb_[8] + l*EDIM;

    inproj_mfma3<<<dim3(64, 4, 2), 256, 0, stream>>>(xf, xr, nwF, nwR, Wip, l, xzF, xzR);
    xprojf_k<<<dim3(64, 1, 2), 256, 0, stream>>>(xzF, xzR, cwF_, cwR_, cbF_, cbR_,
                                                 Wxp, l, xcF, xcR, dbF, dbR);
    scan4_k<<<dim3(256, 1, 2), 256, 0, stream>>>(xzF, xzR, xcF, xcR, dbF, dbR, dwF, dwR,
                                                 dtbF, dtbR, AlF, AlR, DpF, DpR, yoF, yoR);
    outproj_mfma<<<dim3(32, 4, 2), 256, 0, stream>>>(yoF, yoR, Wop, l, xf, xr);
  }

  // 4. head
  head_k<<<dim3(BATCH), 256, 0, stream>>>(xf, xr, fc_w, fc_b, fc2_w, fc2_b, out);
}